// Round 6
// baseline (426.071 us; speedup 1.0000x reference)
//
#include <hip/hip_runtime.h>
#include <stdint.h>

typedef unsigned short u16;
typedef __attribute__((ext_vector_type(8))) short short8;   // 8 x bf16 (4 VGPRs)
typedef __attribute__((ext_vector_type(4))) float f32x4;    // MFMA C/D frag

__device__ __forceinline__ float bf2f(u16 u){
  union { uint32_t i; float f; } v; v.i = ((uint32_t)u) << 16; return v.f;
}
__device__ __forceinline__ u16 f2bf(float f){
  union { float f; uint32_t i; } v; v.f = f;
  uint32_t r = v.i + 0x7FFFu + ((v.i >> 16) & 1u);   // RNE
  return (u16)(r >> 16);
}

// async global->LDS, 16B/lane. LDS dest is the WAVE-UNIFORM base; HW scatters
// lane i to base + i*16. (verified correct r4/r5)
typedef __attribute__((address_space(3))) uint32_t lds_u32;
typedef const __attribute__((address_space(1))) uint32_t gl_u32;
__device__ __forceinline__ void gl_lds16(const void* g, void* lds){
  __builtin_amdgcn_global_load_lds((gl_u32*)g, (lds_u32*)lds, 16, 0, 0);
}

// ---------------------------------------------------------------- casts
__global__ void cast_f32_bf16(const float* __restrict__ src, u16* __restrict__ dst){
  const int i = blockIdx.x * 256 + threadIdx.x;      // 1,048,576 threads
  const float4 a = ((const float4*)src)[2 * i];
  const float4 b = ((const float4*)src)[2 * i + 1];
  uint4 o;
  o.x = (uint32_t)f2bf(a.x) | ((uint32_t)f2bf(a.y) << 16);
  o.y = (uint32_t)f2bf(a.z) | ((uint32_t)f2bf(a.w) << 16);
  o.z = (uint32_t)f2bf(b.x) | ((uint32_t)f2bf(b.y) << 16);
  o.w = (uint32_t)f2bf(b.z) | ((uint32_t)f2bf(b.w) << 16);
  ((uint4*)dst)[i] = o;
}

// ---------------------------------------------------------------- transpose
// src: R x C fp32 row-major  ->  dst: C x R bf16 row-major
__global__ void transpose_f32_bf16(const float* __restrict__ src, u16* __restrict__ dst,
                                   int R, int C){
  __shared__ u16 tile[32][33];
  const int cb = blockIdx.x * 32, rb = blockIdx.y * 32;
  const int tx = threadIdx.x, ty = threadIdx.y;
  #pragma unroll
  for (int i = 0; i < 32; i += 8)
    tile[ty + i][tx] = f2bf(src[(size_t)(rb + ty + i) * C + cb + tx]);
  __syncthreads();
  #pragma unroll
  for (int i = 0; i < 32; i += 8)
    dst[(size_t)(cb + ty + i) * R + rb + tx] = tile[tx][ty + i];
}

// v slice of qkv(bf16) (B,T, 4096 + h*128 + d) -> vT (B,H, D=128, T=2048) bf16
__global__ void transpose_v(const u16* __restrict__ qkv, u16* __restrict__ vT){
  __shared__ u16 tile[32][33];
  const int db = blockIdx.x * 32, tb = blockIdx.y * 32, bh = blockIdx.z;
  const int b = bh >> 4, h = bh & 15;
  const int tx = threadIdx.x, ty = threadIdx.y;
  const u16* src = qkv + (size_t)(b * 2048) * 6144 + 4096 + h * 128;
  #pragma unroll
  for (int i = 0; i < 32; i += 8) tile[ty + i][tx] = src[(size_t)(tb + ty + i) * 6144 + db + tx];
  __syncthreads();
  u16* d = vT + (size_t)bh * 128 * 2048;
  #pragma unroll
  for (int i = 0; i < 32; i += 8) d[(size_t)(db + ty + i) * 2048 + tb + tx] = tile[tx][ty + i];
}

// ---------------------------------------------------------------- RoPE
// q output PRE-SCALED by (1/sqrt(128))*log2(e) so attn's softmax is a bare exp2.
__global__ void rope_qk(const u16* __restrict__ qkv, const float* __restrict__ cosb,
                        const float* __restrict__ sinb, u16* __restrict__ qo,
                        u16* __restrict__ ko){
  const int idx = blockIdx.x * 256 + threadIdx.x;          // 2^23 total
  const int d2 = idx & 63;
  const int h  = (idx >> 6) & 15;
  const int t  = (idx >> 10) & 2047;
  const int b  = (idx >> 21) & 1;
  const int w  = idx >> 22;                                 // 0=q, 1=k
  const int incol = w * 2048 + h * 128 + 2 * d2;
  const uint32_t pair = *(const uint32_t*)(qkv + (size_t)(b * 2048 + t) * 6144 + incol);
  float x1 = bf2f((u16)(pair & 0xffff));
  float x2 = bf2f((u16)(pair >> 16));
  float o1 = x1, o2 = x2;
  if (d2 < 32){
    const float c = cosb[t * 32 + d2];
    const float s = sinb[t * 32 + d2];
    o1 = x1 * c - x2 * s;
    o2 = x1 * s + x2 * c;
  }
  const float qscale = w ? 1.0f : 0.12754100060254310f;   // (1/sqrt(128))*log2(e), q only
  o1 *= qscale; o2 *= qscale;
  const uint32_t outp = (uint32_t)f2bf(o1) | ((uint32_t)f2bf(o2) << 16);
  u16* dst = w ? ko : qo;
  *(uint32_t*)(dst + ((size_t)(b * 16 + h) * 2048 + t) * 128 + 2 * d2) = outp;
}

// ---------------------------------------------------------------- GEMM 128² (legacy, used for gemm2)
// C[M,N] = A[M,K] @ Bt[N,K]^T ; 128x128 tile, BK=64, async gl_lds staging.
// chunked per-XCD tile map (r5, neutral-kept).
template<bool F32OUT>
__global__ __launch_bounds__(256) void gemm_bt(const u16* __restrict__ A,
                                               const u16* __restrict__ Bt,
                                               void* __restrict__ Cv,
                                               int M, int N, int K){
  __shared__ __align__(16) u16 sA[128 * 64];
  __shared__ __align__(16) u16 sB[128 * 64];
  const int tid  = threadIdx.x;
  const int lane = tid & 63, wave = tid >> 6;
  const int quad = lane >> 4, l15 = lane & 15;
  const int wr = wave >> 1, wc = wave & 1;

  const int nx = gridDim.x, ny = gridDim.y;
  const int bid = blockIdx.y * nx + blockIdx.x;
  int brow, bcol;
  if ((nx & 7) == 0){
    const int xcd = bid & 7, c = bid >> 3;
    const int cq = c / ny;
    bcol = xcd * (nx >> 3) + cq;
    brow = c - cq * ny;
  } else { bcol = bid % nx; brow = bid / nx; }
  const int mb = brow * 128, nb = bcol * 128;

  f32x4 acc[4][4];
  #pragma unroll
  for (int i = 0; i < 4; i++)
    #pragma unroll
    for (int j = 0; j < 4; j++) acc[i][j] = (f32x4)0.0f;

  for (int k0 = 0; k0 < K; k0 += 64){
    const u16* Ab = A + (size_t)mb * K + k0;
    const u16* Bb = Bt + (size_t)nb * K + k0;
    #pragma unroll
    for (int r = 0; r < 4; r++){
      const int idx = r * 256 + tid;          // 16B chunk index in tile (1024 total)
      const int row = idx >> 3, c = idx & 7;
      const int gc = (c ^ (row & 7)) * 8;     // swizzled source column (elements)
      gl_lds16(Ab + (size_t)row * K + gc, (char*)sA + r * 4096 + wave * 1024);
      gl_lds16(Bb + (size_t)row * K + gc, (char*)sB + r * 4096 + wave * 1024);
    }
    __syncthreads();
    #pragma unroll
    for (int ks = 0; ks < 2; ks++){
      short8 af[4], bfr[4];
      #pragma unroll
      for (int i = 0; i < 4; i++){
        const int row = wr * 64 + i * 16 + l15;
        const int ch = (ks * 4 + quad) ^ (l15 & 7);
        af[i] = *(const short8*)((const char*)sA + row * 128 + ch * 16);
      }
      #pragma unroll
      for (int j = 0; j < 4; j++){
        const int row = wc * 64 + j * 16 + l15;
        const int ch = (ks * 4 + quad) ^ (l15 & 7);
        bfr[j] = *(const short8*)((const char*)sB + row * 128 + ch * 16);
      }
      #pragma unroll
      for (int i = 0; i < 4; i++)
        #pragma unroll
        for (int j = 0; j < 4; j++)
          acc[i][j] = __builtin_amdgcn_mfma_f32_16x16x32_bf16(af[i], bfr[j], acc[i][j], 0, 0, 0);
    }
    __syncthreads();
  }
  #pragma unroll
  for (int i = 0; i < 4; i++)
    #pragma unroll
    for (int j = 0; j < 4; j++)
      #pragma unroll
      for (int r = 0; r < 4; r++){
        const int row = mb + wr * 64 + i * 16 + quad * 4 + r;
        const int col = nb + wc * 64 + j * 16 + l15;
        if (F32OUT) ((float*)Cv)[(size_t)row * N + col] = acc[i][j][r];
        else        ((u16*)Cv)[(size_t)row * N + col]   = f2bf(acc[i][j][r]);
      }
}

// ---------------------------------------------------------------- GEMM 256x128 (gemm1)
// r6: same verified template (T2 swizzle + counted vmcnt + raw s_barrier +
// setprio), tile aspect changed 256x256 -> 256x128. Grid 48x16 = 768 blocks =
// EXACTLY 3 occupancy rounds on 256 CUs (r5's 256² gave 384 blocks = 1.5 rounds;
// the half-empty round 2 cost ~32us: 130 = 2*tau, ideal 1.5*tau = 97.5).
// LDS 96 KiB: sA 2x(256x64), sB 2x(128x64). 8 waves as 4M x 2N, 64x64/wave,
// acc[4][4]. 2 phases/K-tile x 16 MFMA (same barrier:MFMA density as before).
// Staging per K-tile: A=4 calls (P1->sAn), B=2 calls (P2->sBc, consumed at P1).
// vmcnt: steady outstanding at wait = [A(s+1) x4, B(s+2) x2] -> vmcnt(2);
// prologue A(0)x4,B(0)x2,B(1)x2 -> vmcnt(2); tail s=NT-2 -> vmcnt(0).
__device__ __forceinline__ void stage8k(const u16* __restrict__ g, int ldK,
                                        char* lds, int call, int tid){
  const int idx = call * 512 + tid;                 // 16B chunk id
  const int row = idx >> 3, c = idx & 7;
  gl_lds16(g + (size_t)row * ldK + ((c ^ (row & 7)) * 8),   // pre-swizzled source
           lds + call * 8192 + (tid >> 6) * 1024);          // linear LDS dest
}

template<bool F32OUT>
__global__ __launch_bounds__(512, 2) void gemm256x128(const u16* __restrict__ A,
                                                      const u16* __restrict__ Bt,
                                                      void* __restrict__ Cv,
                                                      int M, int N, int K){
  __shared__ __align__(16) u16 sA[2 * 256 * 64];    // 64 KiB
  __shared__ __align__(16) u16 sB[2 * 128 * 64];    // 32 KiB
  const int tid  = threadIdx.x;
  const int lane = tid & 63, wave = tid >> 6;
  const int quad = lane >> 4, l15 = lane & 15;
  const int wm = wave >> 1, wn = wave & 1;          // 4 x 2 wave grid

  // chunked per-XCD tile map: XCD x owns cols [x*(nx/8)...), rows walked fastest
  const int nx = gridDim.x, ny = gridDim.y;         // 48, 16
  const int bid = blockIdx.y * nx + blockIdx.x;
  int row, col;
  if ((nx & 7) == 0){
    const int xcd = bid & 7, c = bid >> 3;
    const int cq = c / ny;
    col = xcd * (nx >> 3) + cq;
    row = c - cq * ny;
  } else { col = bid % nx; row = bid / nx; }
  const int mb = row * 256, nb = col * 128;

  const int NT = K >> 6;
  const u16* Ab = A  + (size_t)mb * K;
  const u16* Bb = Bt + (size_t)nb * K;

  f32x4 acc[4][4];
  #pragma unroll
  for (int i = 0; i < 4; i++)
    #pragma unroll
    for (int n = 0; n < 4; n++) acc[i][n] = (f32x4)0.0f;

  // prologue: A(0)->sA buf0 (4), B(0)->sB buf0 (2), B(1)->sB buf1 (2)
  #pragma unroll
  for (int r = 0; r < 4; r++) stage8k(Ab, K, (char*)sA, r, tid);
  #pragma unroll
  for (int r = 0; r < 2; r++) stage8k(Bb, K, (char*)sB, r, tid);
  #pragma unroll
  for (int r = 0; r < 2; r++) stage8k(Bb + 64, K, (char*)sB + 16384, r, tid);
  asm volatile("s_waitcnt vmcnt(2)" ::: "memory");   // A(0),B(0) landed; B(1) flying
  __builtin_amdgcn_s_barrier();

  for (int s = 0; s < NT; ++s){
    const int cur = s & 1;
    char* sAc = (char*)sA + cur * 32768;
    char* sBc = (char*)sB + cur * 16384;
    char* sAn = (char*)sA + (cur ^ 1) * 32768;
    const u16* An = Ab + (size_t)(s + 1) * 64;
    const u16* Bn = Bb + (size_t)(s + 2) * 64;
    const bool pfA = (s + 1 < NT), pfB = (s + 2 < NT);

    // ---- P1: all B-frags + A-frags 0,1 ; stage A(s+1) -> sAn
    short8 bq[4][2];
    #pragma unroll
    for (int n = 0; n < 4; n++)
      #pragma unroll
      for (int ks = 0; ks < 2; ks++){
        const int row2 = wn * 64 + n * 16 + l15;
        bq[n][ks] = *(const short8*)(sBc + row2 * 128 +
                                     (((ks * 4 + quad) ^ (l15 & 7)) * 16));
      }
    short8 aqA[2][2];
    #pragma unroll
    for (int i = 0; i < 2; i++)
      #pragma unroll
      for (int ks = 0; ks < 2; ks++){
        const int row2 = wm * 64 + i * 16 + l15;
        aqA[i][ks] = *(const short8*)(sAc + row2 * 128 +
                                      (((ks * 4 + quad) ^ (l15 & 7)) * 16));
      }
    if (pfA){
      stage8k(An, K, sAn, 0, tid); stage8k(An, K, sAn, 1, tid);
      stage8k(An, K, sAn, 2, tid); stage8k(An, K, sAn, 3, tid);
    }
    __builtin_amdgcn_s_barrier();
    asm volatile("s_waitcnt lgkmcnt(0)" ::: "memory");
    __builtin_amdgcn_s_setprio(1);
    #pragma unroll
    for (int ks = 0; ks < 2; ks++)
      #pragma unroll
      for (int i = 0; i < 2; i++)
        #pragma unroll
        for (int n = 0; n < 4; n++)
          acc[i][n] = __builtin_amdgcn_mfma_f32_16x16x32_bf16(
              aqA[i][ks], bq[n][ks], acc[i][n], 0, 0, 0);
    __builtin_amdgcn_s_setprio(0);
    __builtin_amdgcn_s_barrier();

    // ---- P2: A-frags 2,3 ; stage B(s+2) -> sBc (B(s) fully read in P1)
    short8 aqB[2][2];
    #pragma unroll
    for (int i = 0; i < 2; i++)
      #pragma unroll
      for (int ks = 0; ks < 2; ks++){
        const int row2 = wm * 64 + (2 + i) * 16 + l15;
        aqB[i][ks] = *(const short8*)(sAc + row2 * 128 +
                                      (((ks * 4 + quad) ^ (l15 & 7)) * 16));
      }
    if (pfB){ stage8k(Bn, K, sBc, 0, tid); stage8k(Bn, K, sBc, 1, tid); }
    __builtin_amdgcn_s_barrier();
    asm volatile("s_waitcnt lgkmcnt(0)" ::: "memory");
    __builtin_amdgcn_s_setprio(1);
    #pragma unroll
    for (int ks = 0; ks < 2; ks++)
      #pragma unroll
      for (int i = 0; i < 2; i++)
        #pragma unroll
        for (int n = 0; n < 4; n++)
          acc[2 + i][n] = __builtin_amdgcn_mfma_f32_16x16x32_bf16(
              aqB[i][ks], bq[n][ks], acc[2 + i][n], 0, 0, 0);
    __builtin_amdgcn_s_setprio(0);
    if (pfB)      asm volatile("s_waitcnt vmcnt(2)" ::: "memory");  // steady: never 0
    else if (pfA) asm volatile("s_waitcnt vmcnt(0)" ::: "memory");  // tail
    __builtin_amdgcn_s_barrier();
  }

  #pragma unroll
  for (int i = 0; i < 4; i++)
    #pragma unroll
    for (int n = 0; n < 4; n++)
      #pragma unroll
      for (int r = 0; r < 4; r++){
        const int row2 = mb + wm * 64 + i * 16 + quad * 4 + r;
        const int col2 = nb + wn * 64 + n * 16 + l15;
        if (F32OUT) ((float*)Cv)[(size_t)row2 * N + col2] = acc[i][n][r];
        else        ((u16*)Cv)[(size_t)row2 * N + col2]   = f2bf(acc[i][n][r]);
      }
}

// ---------------------------------------------------------------- flash attention v5
// q,k: (BH, T, 128) bf16 ; vT: (BH, 128, T) bf16 ; y: (B, T, C) bf16
// Q-tile 128 (32 rows/wave), KV-tile 64, 512 blocks = 2/CU exact.
// NO-MAX softmax; q arrives pre-scaled by (1/sqrt(128))*log2(e) -> bare exp2f.
__global__ __launch_bounds__(256, 2) void attn(const u16* __restrict__ q,
                                               const u16* __restrict__ k,
                                               const u16* __restrict__ vT,
                                               u16* __restrict__ y){
  __shared__ __align__(16) u16 bufK[64 * 128];        // 16 KB: Q staging, then K[kt]
  __shared__ __align__(16) u16 bufV[128 * 64];        // 16 KB: V[kt] (d rows, t cols)
  __shared__ __align__(16) u16 bufP[4 * 32 * 64];     // 16 KB: P, per-wave private
  const int tid  = threadIdx.x;
  const int lane = tid & 63, wave = tid >> 6;
  const int quad = lane >> 4, l15 = lane & 15;
  const int bh = blockIdx.x & 31, qt = blockIdx.x >> 5;   // bh co-XCD swizzle, qt 0..15
  const u16* qbh = q  + (size_t)bh * 2048 * 128;
  const u16* kbh = k  + (size_t)bh * 2048 * 128;
  const u16* vbh = vT + (size_t)bh * 128 * 2048;

  // ---- stage Q tile (128x128) in two 64-row passes through bufK; wave w owns
  // rows w*32..w*32+31 -> pass p = w>>1, local base (w&1)*32.
  short8 qf[2][4];
  #pragma unroll
  for (int p = 0; p < 2; p++){
    #pragma unroll
    for (int rr = 0; rr < 4; rr++){
      const int idx = rr * 256 + tid;
      const int row = idx >> 4, c = idx & 15;
      gl_lds16(qbh + (size_t)(qt * 128 + p * 64 + row) * 128 + ((c ^ (row & 15)) * 8),
               (char*)bufK + rr * 4096 + wave * 1024);
    }
    __syncthreads();
    if ((wave >> 1) == p){
      const int rbase = (wave & 1) * 32;
      #pragma unroll
      for (int i = 0; i < 2; i++)
        #pragma unroll
        for (int ks = 0; ks < 4; ks++){
          const int row = rbase + i * 16 + l15;       // row&15 == l15
          const int ch = (ks * 4 + quad) ^ l15;
          qf[i][ks] = *(const short8*)((const char*)bufK + row * 256 + ch * 16);
        }
    }
    __syncthreads();
  }

  // prologue: K[0] (drain), then V[0] (flies into first QK)
  #pragma unroll
  for (int rr = 0; rr < 4; rr++){
    const int idx = rr * 256 + tid;
    const int row = idx >> 4, c = idx & 15;
    gl_lds16(kbh + (size_t)row * 128 + ((c ^ (row & 15)) * 8),
             (char*)bufK + rr * 4096 + wave * 1024);
  }
  __syncthreads();
  #pragma unroll
  for (int rr = 0; rr < 4; rr++){
    const int idx = rr * 256 + tid;
    const int row = idx >> 3, c = idx & 7;     // row = d (0..127)
    gl_lds16(vbh + (size_t)row * 2048 + ((c ^ (row & 7)) * 8),
             (char*)bufV + rr * 4096 + wave * 1024);
  }

  f32x4 o[2][8];
  #pragma unroll
  for (int i = 0; i < 2; i++)
    #pragma unroll
    for (int ds = 0; ds < 8; ds++) o[i][ds] = (f32x4)0.0f;
  float l_[2][4] = {{0,0,0,0},{0,0,0,0}};     // per-lane partial row sums

  for (int kt = 0; kt < 32; kt++){
    // S = Q @ K^T   (K[kt] in bufK; V[kt] flying)
    f32x4 s[2][4];
    #pragma unroll
    for (int i = 0; i < 2; i++)
      #pragma unroll
      for (int kv = 0; kv < 4; kv++) s[i][kv] = (f32x4)0.0f;
    #pragma unroll
    for (int ks = 0; ks < 4; ks++){
      short8 bfr[4];
      #pragma unroll
      for (int kv = 0; kv < 4; kv++){
        const int row = kv * 16 + l15;
        const int ch = (ks * 4 + quad) ^ l15;  // row&15 == l15
        bfr[kv] = *(const short8*)((const char*)bufK + row * 256 + ch * 16);
      }
      #pragma unroll
      for (int i = 0; i < 2; i++)
        #pragma unroll
        for (int kv = 0; kv < 4; kv++)
          s[i][kv] = __builtin_amdgcn_mfma_f32_16x16x32_bf16(qf[i][ks], bfr[kv], s[i][kv], 0, 0, 0);
    }

    // no-max softmax: p = 2^s (q pre-scaled); accumulate per-lane partial l
    #pragma unroll
    for (int i = 0; i < 2; i++)
      #pragma unroll
      for (int kv = 0; kv < 4; kv++)
        #pragma unroll
        for (int r = 0; r < 4; r++){
          const float p = exp2f(s[i][kv][r]);
          s[i][kv][r] = p;
          l_[i][r] += p;
        }

    __syncthreads();   // all QK reads of bufK done; V[kt] drained (vmcnt0)

    // issue K[kt+1] — flies during P-write + PV
    if (kt < 31){
      #pragma unroll
      for (int rr = 0; rr < 4; rr++){
        const int idx = rr * 256 + tid;
        const int row = idx >> 4, c = idx & 15;
        gl_lds16(kbh + (size_t)((kt + 1) * 64 + row) * 128 + ((c ^ (row & 15)) * 8),
                 (char*)bufK + rr * 4096 + wave * 1024);
      }
    }

    // write P (per-wave private 4KB region; lgkmcnt dependency only)
    #pragma unroll
    for (int i = 0; i < 2; i++)
      #pragma unroll
      for (int kv = 0; kv < 4; kv++)
        #pragma unroll
        for (int r = 0; r < 4; r++){
          const int row = i * 16 + quad * 4 + r;  // 0..31
          const int col = kv * 16 + l15;          // 0..63
          bufP[wave * 2048 + row * 64 + (((col >> 3) ^ (row & 7)) * 8) + (col & 7)]
            = f2bf(s[i][kv][r]);
        }

    // O += P @ V   (V[kt] in bufV; K[kt+1] flying)
    #pragma unroll
    for (int ks = 0; ks < 2; ks++){
      short8 pa[2];
      #pragma unroll
      for (int i = 0; i < 2; i++)
        pa[i] = *(const short8*)((const char*)bufP + wave * 4096 + (i * 16 + l15) * 128 +
                                 (((ks * 4 + quad) ^ (l15 & 7)) * 16));
      short8 vb[8];
      #pragma unroll
      for (int ds = 0; ds < 8; ds++){
        const int row = ds * 16 + l15;         // d row
        const int ch = (ks * 4 + quad) ^ (row & 7);
        vb[ds] = *(const short8*)((const char*)bufV + row * 128 + ch * 16);
      }
      #pragma unroll
      for (int ds = 0; ds < 8; ds++)
        #pragma unroll
        for (int i = 0; i < 2; i++)
          o[i][ds] = __builtin_amdgcn_mfma_f32_16x16x32_bf16(pa[i], vb[ds], o[i][ds], 0, 0, 0);
    }

    __syncthreads();   // PV reads of bufV done; K[kt+1] drained

    // issue V[kt+1] — flies during next QK + softmax
    if (kt < 31){
      #pragma unroll
      for (int rr = 0; rr < 4; rr++){
        const int idx = rr * 256 + tid;
        const int row = idx >> 3, c = idx & 7;
        gl_lds16(vbh + (size_t)row * 2048 + (kt + 1) * 64 + ((c ^ (row & 7)) * 8),
                 (char*)bufV + rr * 4096 + wave * 1024);
      }
    }
  }

  // one cross-lane reduce of l over the 16-lane column group (quad preserved)
  #pragma unroll
  for (int i = 0; i < 2; i++)
    #pragma unroll
    for (int r = 0; r < 4; r++){
      #pragma unroll
      for (int off = 1; off < 16; off <<= 1) l_[i][r] += __shfl_xor(l_[i][r], off);
    }

  // epilogue: y[b, t, h*128 + d] = o / l
  const int b = bh >> 4, h = bh & 15;
  float inv[2][4];
  #pragma unroll
  for (int i = 0; i < 2; i++)
    #pragma unroll
    for (int r = 0; r < 4; r++) inv[i][r] = 1.0f / l_[i][r];
  #pragma unroll
  for (int i = 0; i < 2; i++)
    #pragma unroll
    for (int ds = 0; ds < 8; ds++)
      #pragma unroll
      for (int r = 0; r < 4; r++){
        const int t = qt * 128 + wave * 32 + i * 16 + quad * 4 + r;
        const int cc = h * 128 + ds * 16 + l15;
        y[((size_t)(b * 2048 + t)) * 2048 + cc] = f2bf(o[i][ds][r] * inv[i][r]);
      }
}

// ---------------------------------------------------------------- launcher
extern "C" void kernel_launch(void* const* d_in, const int* in_sizes, int n_in,
                              void* d_out, int out_size, void* d_ws, size_t ws_size,
                              hipStream_t stream) {
  const float* x    = (const float*)d_in[0];   // (2,2048,2048) fp32
  const float* Wa   = (const float*)d_in[1];   // (2048,6144) fp32
  const float* Wp   = (const float*)d_in[2];   // (2048,2048) fp32
  const float* cosb = (const float*)d_in[3];   // (2048,32) fp32
  const float* sinb = (const float*)d_in[4];   // (2048,32) fp32
  float* out = (float*)d_out;                  // (2,2048,2048) fp32
  char* ws = (char*)d_ws;

  u16* WaT = (u16*)(ws);                   // 6144x2048 bf16   25165824 B
  u16* WpT = (u16*)(ws + 25165824);        // 2048x2048 bf16    8388608 B
  u16* xb  = (u16*)(ws + 33554432);        // 4096x2048 bf16   16777216 B (dead after gemm1)
  u16* qkv = (u16*)(ws + 50331648);        // 4096x6144 bf16   50331648 B
  u16* qb  = (u16*)(ws + 100663296);       // (32,2048,128)    16777216 B
  u16* kb  = (u16*)(ws + 117440512);       //                  16777216 B
  u16* vTb = (u16*)(ws + 134217728);       // (32,128,2048)    16777216 B
  u16* yb  = (u16*)(ws + 33554432);        // 4096x2048 bf16 — reuses xb slot

  dim3 b32(32, 8, 1);
  transpose_f32_bf16<<<dim3(192, 64, 1), b32, 0, stream>>>(Wa, WaT, 2048, 6144);
  transpose_f32_bf16<<<dim3(64, 64, 1),  b32, 0, stream>>>(Wp, WpT, 2048, 2048);
  cast_f32_bf16<<<4096, 256, 0, stream>>>(x, xb);
  gemm256x128<false><<<dim3(48, 16, 1), 512, 0, stream>>>(xb, WaT, qkv, 4096, 6144, 2048);
  rope_qk<<<32768, 256, 0, stream>>>(qkv, cosb, sinb, qb, kb);
  transpose_v<<<dim3(4, 64, 32), b32, 0, stream>>>(qkv, vTb);
  attn<<<512, 256, 0, stream>>>(qb, kb, vTb, yb);
  gemm_bt<true><<<dim3(16, 32, 1), 256, 0, stream>>>(yb, WpT, out, 4096, 2048, 2048);
}

// Round 7
// 408.907 us; speedup vs baseline: 1.0420x; 1.0420x over previous
//
#include <hip/hip_runtime.h>
#include <stdint.h>

typedef unsigned short u16;
typedef __attribute__((ext_vector_type(8))) short short8;   // 8 x bf16 (4 VGPRs)
typedef __attribute__((ext_vector_type(4))) float f32x4;    // MFMA C/D frag

__device__ __forceinline__ float bf2f(u16 u){
  union { uint32_t i; float f; } v; v.i = ((uint32_t)u) << 16; return v.f;
}
__device__ __forceinline__ u16 f2bf(float f){
  union { float f; uint32_t i; } v; v.f = f;
  uint32_t r = v.i + 0x7FFFu + ((v.i >> 16) & 1u);   // RNE
  return (u16)(r >> 16);
}

// async global->LDS, 16B/lane. LDS dest is the WAVE-UNIFORM base; HW scatters
// lane i to base + i*16. (verified correct)
typedef __attribute__((address_space(3))) uint32_t lds_u32;
typedef const __attribute__((address_space(1))) uint32_t gl_u32;
__device__ __forceinline__ void gl_lds16(const void* g, void* lds){
  __builtin_amdgcn_global_load_lds((gl_u32*)g, (lds_u32*)lds, 16, 0, 0);
}

// ---------------------------------------------------------------- prep (merged)
// r7: cast(x) + transpose(Wa) + transpose(Wp) in ONE dispatch. The ~160us
// residual between sum-of-heavy-kernels and total is the small-kernel chain +
// ~10us/dispatch launch gaps (stable across r0-r6). Merging independent jobs
// cuts dispatches 8->5 at zero occupancy/algorithm risk (bodies unchanged,
// flat-tid remap only).
__global__ __launch_bounds__(256) void prep(const float* __restrict__ x,  u16* __restrict__ xb,
                                            const float* __restrict__ Wa, u16* __restrict__ WaT,
                                            const float* __restrict__ Wp, u16* __restrict__ WpT){
  const int gb = blockIdx.x;
  const int tid = threadIdx.x;
  if (gb < 4096){                       // ---- cast x -> xb (bf16), float4 x2
    const int i = gb * 256 + tid;
    const float4 a = ((const float4*)x)[2 * i];
    const float4 b = ((const float4*)x)[2 * i + 1];
    uint4 o;
    o.x = (uint32_t)f2bf(a.x) | ((uint32_t)f2bf(a.y) << 16);
    o.y = (uint32_t)f2bf(a.z) | ((uint32_t)f2bf(a.w) << 16);
    o.z = (uint32_t)f2bf(b.x) | ((uint32_t)f2bf(b.y) << 16);
    o.w = (uint32_t)f2bf(b.z) | ((uint32_t)f2bf(b.w) << 16);
    ((uint4*)xb)[i] = o;
    return;
  }
  // ---- weight transposes: R x C fp32 -> C x R bf16
  __shared__ u16 tile[32][33];
  const int tx = tid & 31, ty = tid >> 5;
  const float* src; u16* dst; int R, C, cb, rb;
  if (gb < 16384){                      // Wa: 192 x 64 tiles
    const int b = gb - 4096;
    cb = (b % 192) * 32; rb = (b / 192) * 32; src = Wa; dst = WaT; R = 2048; C = 6144;
  } else {                              // Wp: 64 x 64 tiles
    const int b = gb - 16384;
    cb = (b % 64) * 32;  rb = (b / 64) * 32;  src = Wp; dst = WpT; R = 2048; C = 2048;
  }
  #pragma unroll
  for (int i = 0; i < 32; i += 8)
    tile[ty + i][tx] = f2bf(src[(size_t)(rb + ty + i) * C + cb + tx]);
  __syncthreads();
  #pragma unroll
  for (int i = 0; i < 32; i += 8)
    dst[(size_t)(cb + ty + i) * R + rb + tx] = tile[tx][ty + i];
}

// ---------------------------------------------------------------- rope_tv (merged)
// r7: rope_qk + transpose_v in ONE dispatch (both read qkv, disjoint outputs).
// q output PRE-SCALED by (1/sqrt(128))*log2(e) so attn's softmax is a bare exp2.
__global__ __launch_bounds__(256) void rope_tv(const u16* __restrict__ qkv,
                                               const float* __restrict__ cosb,
                                               const float* __restrict__ sinb,
                                               u16* __restrict__ qo, u16* __restrict__ ko,
                                               u16* __restrict__ vT){
  const int gb = blockIdx.x;
  const int tid = threadIdx.x;
  if (gb < 32768){                      // ---- RoPE on q,k
    const int idx = gb * 256 + tid;     // 2^23 total
    const int d2 = idx & 63;
    const int h  = (idx >> 6) & 15;
    const int t  = (idx >> 10) & 2047;
    const int b  = (idx >> 21) & 1;
    const int w  = idx >> 22;           // 0=q, 1=k
    const int incol = w * 2048 + h * 128 + 2 * d2;
    const uint32_t pair = *(const uint32_t*)(qkv + (size_t)(b * 2048 + t) * 6144 + incol);
    float x1 = bf2f((u16)(pair & 0xffff));
    float x2 = bf2f((u16)(pair >> 16));
    float o1 = x1, o2 = x2;
    if (d2 < 32){
      const float c = cosb[t * 32 + d2];
      const float s = sinb[t * 32 + d2];
      o1 = x1 * c - x2 * s;
      o2 = x1 * s + x2 * c;
    }
    const float qscale = w ? 1.0f : 0.12754100060254310f;   // (1/sqrt(128))*log2(e)
    o1 *= qscale; o2 *= qscale;
    const uint32_t outp = (uint32_t)f2bf(o1) | ((uint32_t)f2bf(o2) << 16);
    u16* dst = w ? ko : qo;
    *(uint32_t*)(dst + ((size_t)(b * 16 + h) * 2048 + t) * 128 + 2 * d2) = outp;
    return;
  }
  // ---- transpose v slice: qkv(B,T, 4096+h*128+d) -> vT (B,H, 128, 2048)
  __shared__ u16 tile[32][33];
  const int b2 = gb - 32768;            // 8192 blocks: db 4 | tb 64 | bh 32
  const int db = (b2 & 3) * 32, tb = ((b2 >> 2) & 63) * 32, bh = b2 >> 8;
  const int b = bh >> 4, h = bh & 15;
  const int tx = tid & 31, ty = tid >> 5;
  const u16* src = qkv + (size_t)(b * 2048) * 6144 + 4096 + h * 128;
  #pragma unroll
  for (int i = 0; i < 32; i += 8) tile[ty + i][tx] = src[(size_t)(tb + ty + i) * 6144 + db + tx];
  __syncthreads();
  u16* d = vT + (size_t)bh * 128 * 2048;
  #pragma unroll
  for (int i = 0; i < 32; i += 8) d[(size_t)(db + ty + i) * 2048 + tb + tx] = tile[tx][ty + i];
}

// ---------------------------------------------------------------- GEMM 128² (legacy, used for gemm2)
// C[M,N] = A[M,K] @ Bt[N,K]^T ; 128x128 tile, BK=64, async gl_lds staging.
// chunked per-XCD tile map (r5, neutral-kept).
template<bool F32OUT>
__global__ __launch_bounds__(256) void gemm_bt(const u16* __restrict__ A,
                                               const u16* __restrict__ Bt,
                                               void* __restrict__ Cv,
                                               int M, int N, int K){
  __shared__ __align__(16) u16 sA[128 * 64];
  __shared__ __align__(16) u16 sB[128 * 64];
  const int tid  = threadIdx.x;
  const int lane = tid & 63, wave = tid >> 6;
  const int quad = lane >> 4, l15 = lane & 15;
  const int wr = wave >> 1, wc = wave & 1;

  const int nx = gridDim.x, ny = gridDim.y;
  const int bid = blockIdx.y * nx + blockIdx.x;
  int brow, bcol;
  if ((nx & 7) == 0){
    const int xcd = bid & 7, c = bid >> 3;
    const int cq = c / ny;
    bcol = xcd * (nx >> 3) + cq;
    brow = c - cq * ny;
  } else { bcol = bid % nx; brow = bid / nx; }
  const int mb = brow * 128, nb = bcol * 128;

  f32x4 acc[4][4];
  #pragma unroll
  for (int i = 0; i < 4; i++)
    #pragma unroll
    for (int j = 0; j < 4; j++) acc[i][j] = (f32x4)0.0f;

  for (int k0 = 0; k0 < K; k0 += 64){
    const u16* Ab = A + (size_t)mb * K + k0;
    const u16* Bb = Bt + (size_t)nb * K + k0;
    #pragma unroll
    for (int r = 0; r < 4; r++){
      const int idx = r * 256 + tid;          // 16B chunk index in tile (1024 total)
      const int row = idx >> 3, c = idx & 7;
      const int gc = (c ^ (row & 7)) * 8;     // swizzled source column (elements)
      gl_lds16(Ab + (size_t)row * K + gc, (char*)sA + r * 4096 + wave * 1024);
      gl_lds16(Bb + (size_t)row * K + gc, (char*)sB + r * 4096 + wave * 1024);
    }
    __syncthreads();
    #pragma unroll
    for (int ks = 0; ks < 2; ks++){
      short8 af[4], bfr[4];
      #pragma unroll
      for (int i = 0; i < 4; i++){
        const int row = wr * 64 + i * 16 + l15;
        const int ch = (ks * 4 + quad) ^ (l15 & 7);
        af[i] = *(const short8*)((const char*)sA + row * 128 + ch * 16);
      }
      #pragma unroll
      for (int j = 0; j < 4; j++){
        const int row = wc * 64 + j * 16 + l15;
        const int ch = (ks * 4 + quad) ^ (l15 & 7);
        bfr[j] = *(const short8*)((const char*)sB + row * 128 + ch * 16);
      }
      #pragma unroll
      for (int i = 0; i < 4; i++)
        #pragma unroll
        for (int j = 0; j < 4; j++)
          acc[i][j] = __builtin_amdgcn_mfma_f32_16x16x32_bf16(af[i], bfr[j], acc[i][j], 0, 0, 0);
    }
    __syncthreads();
  }
  #pragma unroll
  for (int i = 0; i < 4; i++)
    #pragma unroll
    for (int j = 0; j < 4; j++)
      #pragma unroll
      for (int r = 0; r < 4; r++){
        const int row = mb + wr * 64 + i * 16 + quad * 4 + r;
        const int col = nb + wc * 64 + j * 16 + l15;
        if (F32OUT) ((float*)Cv)[(size_t)row * N + col] = acc[i][j][r];
        else        ((u16*)Cv)[(size_t)row * N + col]   = f2bf(acc[i][j][r]);
      }
}

// ---------------------------------------------------------------- GEMM 256x128 (gemm1)
// r6 (kept): 48x16 grid = 768 blocks = exactly 3 occupancy rounds, zero tail.
// Steady rate 832 TF (r6 measured) — phase-density-limited (32 MFMA/K-tile/wave);
// aspect tuning frozen, this is the better measured point (124 vs 130 us).
__device__ __forceinline__ void stage8k(const u16* __restrict__ g, int ldK,
                                        char* lds, int call, int tid){
  const int idx = call * 512 + tid;                 // 16B chunk id
  const int row = idx >> 3, c = idx & 7;
  gl_lds16(g + (size_t)row * ldK + ((c ^ (row & 7)) * 8),   // pre-swizzled source
           lds + call * 8192 + (tid >> 6) * 1024);          // linear LDS dest
}

template<bool F32OUT>
__global__ __launch_bounds__(512, 2) void gemm256x128(const u16* __restrict__ A,
                                                      const u16* __restrict__ Bt,
                                                      void* __restrict__ Cv,
                                                      int M, int N, int K){
  __shared__ __align__(16) u16 sA[2 * 256 * 64];    // 64 KiB
  __shared__ __align__(16) u16 sB[2 * 128 * 64];    // 32 KiB
  const int tid  = threadIdx.x;
  const int lane = tid & 63, wave = tid >> 6;
  const int quad = lane >> 4, l15 = lane & 15;
  const int wm = wave >> 1, wn = wave & 1;          // 4 x 2 wave grid

  const int nx = gridDim.x, ny = gridDim.y;         // 48, 16
  const int bid = blockIdx.y * nx + blockIdx.x;
  int row, col;
  if ((nx & 7) == 0){
    const int xcd = bid & 7, c = bid >> 3;
    const int cq = c / ny;
    col = xcd * (nx >> 3) + cq;
    row = c - cq * ny;
  } else { col = bid % nx; row = bid / nx; }
  const int mb = row * 256, nb = col * 128;

  const int NT = K >> 6;
  const u16* Ab = A  + (size_t)mb * K;
  const u16* Bb = Bt + (size_t)nb * K;

  f32x4 acc[4][4];
  #pragma unroll
  for (int i = 0; i < 4; i++)
    #pragma unroll
    for (int n = 0; n < 4; n++) acc[i][n] = (f32x4)0.0f;

  // prologue: A(0)->sA buf0 (4), B(0)->sB buf0 (2), B(1)->sB buf1 (2)
  #pragma unroll
  for (int r = 0; r < 4; r++) stage8k(Ab, K, (char*)sA, r, tid);
  #pragma unroll
  for (int r = 0; r < 2; r++) stage8k(Bb, K, (char*)sB, r, tid);
  #pragma unroll
  for (int r = 0; r < 2; r++) stage8k(Bb + 64, K, (char*)sB + 16384, r, tid);
  asm volatile("s_waitcnt vmcnt(2)" ::: "memory");   // A(0),B(0) landed; B(1) flying
  __builtin_amdgcn_s_barrier();

  for (int s = 0; s < NT; ++s){
    const int cur = s & 1;
    char* sAc = (char*)sA + cur * 32768;
    char* sBc = (char*)sB + cur * 16384;
    char* sAn = (char*)sA + (cur ^ 1) * 32768;
    const u16* An = Ab + (size_t)(s + 1) * 64;
    const u16* Bn = Bb + (size_t)(s + 2) * 64;
    const bool pfA = (s + 1 < NT), pfB = (s + 2 < NT);

    // ---- P1: all B-frags + A-frags 0,1 ; stage A(s+1) -> sAn
    short8 bq[4][2];
    #pragma unroll
    for (int n = 0; n < 4; n++)
      #pragma unroll
      for (int ks = 0; ks < 2; ks++){
        const int row2 = wn * 64 + n * 16 + l15;
        bq[n][ks] = *(const short8*)(sBc + row2 * 128 +
                                     (((ks * 4 + quad) ^ (l15 & 7)) * 16));
      }
    short8 aqA[2][2];
    #pragma unroll
    for (int i = 0; i < 2; i++)
      #pragma unroll
      for (int ks = 0; ks < 2; ks++){
        const int row2 = wm * 64 + i * 16 + l15;
        aqA[i][ks] = *(const short8*)(sAc + row2 * 128 +
                                      (((ks * 4 + quad) ^ (l15 & 7)) * 16));
      }
    if (pfA){
      stage8k(An, K, sAn, 0, tid); stage8k(An, K, sAn, 1, tid);
      stage8k(An, K, sAn, 2, tid); stage8k(An, K, sAn, 3, tid);
    }
    __builtin_amdgcn_s_barrier();
    asm volatile("s_waitcnt lgkmcnt(0)" ::: "memory");
    __builtin_amdgcn_s_setprio(1);
    #pragma unroll
    for (int ks = 0; ks < 2; ks++)
      #pragma unroll
      for (int i = 0; i < 2; i++)
        #pragma unroll
        for (int n = 0; n < 4; n++)
          acc[i][n] = __builtin_amdgcn_mfma_f32_16x16x32_bf16(
              aqA[i][ks], bq[n][ks], acc[i][n], 0, 0, 0);
    __builtin_amdgcn_s_setprio(0);
    __builtin_amdgcn_s_barrier();

    // ---- P2: A-frags 2,3 ; stage B(s+2) -> sBc (B(s) fully read in P1)
    short8 aqB[2][2];
    #pragma unroll
    for (int i = 0; i < 2; i++)
      #pragma unroll
      for (int ks = 0; ks < 2; ks++){
        const int row2 = wm * 64 + (2 + i) * 16 + l15;
        aqB[i][ks] = *(const short8*)(sAc + row2 * 128 +
                                      (((ks * 4 + quad) ^ (l15 & 7)) * 16));
      }
    if (pfB){ stage8k(Bn, K, sBc, 0, tid); stage8k(Bn, K, sBc, 1, tid); }
    __builtin_amdgcn_s_barrier();
    asm volatile("s_waitcnt lgkmcnt(0)" ::: "memory");
    __builtin_amdgcn_s_setprio(1);
    #pragma unroll
    for (int ks = 0; ks < 2; ks++)
      #pragma unroll
      for (int i = 0; i < 2; i++)
        #pragma unroll
        for (int n = 0; n < 4; n++)
          acc[2 + i][n] = __builtin_amdgcn_mfma_f32_16x16x32_bf16(
              aqB[i][ks], bq[n][ks], acc[2 + i][n], 0, 0, 0);
    __builtin_amdgcn_s_setprio(0);
    if (pfB)      asm volatile("s_waitcnt vmcnt(2)" ::: "memory");  // steady: never 0
    else if (pfA) asm volatile("s_waitcnt vmcnt(0)" ::: "memory");  // tail
    __builtin_amdgcn_s_barrier();
  }

  #pragma unroll
  for (int i = 0; i < 4; i++)
    #pragma unroll
    for (int n = 0; n < 4; n++)
      #pragma unroll
      for (int r = 0; r < 4; r++){
        const int row2 = mb + wm * 64 + i * 16 + quad * 4 + r;
        const int col2 = nb + wn * 64 + n * 16 + l15;
        if (F32OUT) ((float*)Cv)[(size_t)row2 * N + col2] = acc[i][n][r];
        else        ((u16*)Cv)[(size_t)row2 * N + col2]   = f2bf(acc[i][n][r]);
      }
}

// ---------------------------------------------------------------- flash attention v5
// q,k: (BH, T, 128) bf16 ; vT: (BH, 128, T) bf16 ; y: (B, T, C) bf16
// Q-tile 128 (32 rows/wave), KV-tile 64, 512 blocks = 2/CU exact.
// NO-MAX softmax; q arrives pre-scaled by (1/sqrt(128))*log2(e) -> bare exp2f.
__global__ __launch_bounds__(256, 2) void attn(const u16* __restrict__ q,
                                               const u16* __restrict__ k,
                                               const u16* __restrict__ vT,
                                               u16* __restrict__ y){
  __shared__ __align__(16) u16 bufK[64 * 128];        // 16 KB: Q staging, then K[kt]
  __shared__ __align__(16) u16 bufV[128 * 64];        // 16 KB: V[kt] (d rows, t cols)
  __shared__ __align__(16) u16 bufP[4 * 32 * 64];     // 16 KB: P, per-wave private
  const int tid  = threadIdx.x;
  const int lane = tid & 63, wave = tid >> 6;
  const int quad = lane >> 4, l15 = lane & 15;
  const int bh = blockIdx.x & 31, qt = blockIdx.x >> 5;   // bh co-XCD swizzle, qt 0..15
  const u16* qbh = q  + (size_t)bh * 2048 * 128;
  const u16* kbh = k  + (size_t)bh * 2048 * 128;
  const u16* vbh = vT + (size_t)bh * 128 * 2048;

  // ---- stage Q tile (128x128) in two 64-row passes through bufK; wave w owns
  // rows w*32..w*32+31 -> pass p = w>>1, local base (w&1)*32.
  short8 qf[2][4];
  #pragma unroll
  for (int p = 0; p < 2; p++){
    #pragma unroll
    for (int rr = 0; rr < 4; rr++){
      const int idx = rr * 256 + tid;
      const int row = idx >> 4, c = idx & 15;
      gl_lds16(qbh + (size_t)(qt * 128 + p * 64 + row) * 128 + ((c ^ (row & 15)) * 8),
               (char*)bufK + rr * 4096 + wave * 1024);
    }
    __syncthreads();
    if ((wave >> 1) == p){
      const int rbase = (wave & 1) * 32;
      #pragma unroll
      for (int i = 0; i < 2; i++)
        #pragma unroll
        for (int ks = 0; ks < 4; ks++){
          const int row = rbase + i * 16 + l15;       // row&15 == l15
          const int ch = (ks * 4 + quad) ^ l15;
          qf[i][ks] = *(const short8*)((const char*)bufK + row * 256 + ch * 16);
        }
    }
    __syncthreads();
  }

  // prologue: K[0] (drain), then V[0] (flies into first QK)
  #pragma unroll
  for (int rr = 0; rr < 4; rr++){
    const int idx = rr * 256 + tid;
    const int row = idx >> 4, c = idx & 15;
    gl_lds16(kbh + (size_t)row * 128 + ((c ^ (row & 15)) * 8),
             (char*)bufK + rr * 4096 + wave * 1024);
  }
  __syncthreads();
  #pragma unroll
  for (int rr = 0; rr < 4; rr++){
    const int idx = rr * 256 + tid;
    const int row = idx >> 3, c = idx & 7;     // row = d (0..127)
    gl_lds16(vbh + (size_t)row * 2048 + ((c ^ (row & 7)) * 8),
             (char*)bufV + rr * 4096 + wave * 1024);
  }

  f32x4 o[2][8];
  #pragma unroll
  for (int i = 0; i < 2; i++)
    #pragma unroll
    for (int ds = 0; ds < 8; ds++) o[i][ds] = (f32x4)0.0f;
  float l_[2][4] = {{0,0,0,0},{0,0,0,0}};     // per-lane partial row sums

  for (int kt = 0; kt < 32; kt++){
    // S = Q @ K^T   (K[kt] in bufK; V[kt] flying)
    f32x4 s[2][4];
    #pragma unroll
    for (int i = 0; i < 2; i++)
      #pragma unroll
      for (int kv = 0; kv < 4; kv++) s[i][kv] = (f32x4)0.0f;
    #pragma unroll
    for (int ks = 0; ks < 4; ks++){
      short8 bfr[4];
      #pragma unroll
      for (int kv = 0; kv < 4; kv++){
        const int row = kv * 16 + l15;
        const int ch = (ks * 4 + quad) ^ l15;  // row&15 == l15
        bfr[kv] = *(const short8*)((const char*)bufK + row * 256 + ch * 16);
      }
      #pragma unroll
      for (int i = 0; i < 2; i++)
        #pragma unroll
        for (int kv = 0; kv < 4; kv++)
          s[i][kv] = __builtin_amdgcn_mfma_f32_16x16x32_bf16(qf[i][ks], bfr[kv], s[i][kv], 0, 0, 0);
    }

    // no-max softmax: p = 2^s (q pre-scaled); accumulate per-lane partial l
    #pragma unroll
    for (int i = 0; i < 2; i++)
      #pragma unroll
      for (int kv = 0; kv < 4; kv++)
        #pragma unroll
        for (int r = 0; r < 4; r++){
          const float p = exp2f(s[i][kv][r]);
          s[i][kv][r] = p;
          l_[i][r] += p;
        }

    __syncthreads();   // all QK reads of bufK done; V[kt] drained (vmcnt0)

    // issue K[kt+1] — flies during P-write + PV
    if (kt < 31){
      #pragma unroll
      for (int rr = 0; rr < 4; rr++){
        const int idx = rr * 256 + tid;
        const int row = idx >> 4, c = idx & 15;
        gl_lds16(kbh + (size_t)((kt + 1) * 64 + row) * 128 + ((c ^ (row & 15)) * 8),
                 (char*)bufK + rr * 4096 + wave * 1024);
      }
    }

    // write P (per-wave private 4KB region; lgkmcnt dependency only)
    #pragma unroll
    for (int i = 0; i < 2; i++)
      #pragma unroll
      for (int kv = 0; kv < 4; kv++)
        #pragma unroll
        for (int r = 0; r < 4; r++){
          const int row = i * 16 + quad * 4 + r;  // 0..31
          const int col = kv * 16 + l15;          // 0..63
          bufP[wave * 2048 + row * 64 + (((col >> 3) ^ (row & 7)) * 8) + (col & 7)]
            = f2bf(s[i][kv][r]);
        }

    // O += P @ V   (V[kt] in bufV; K[kt+1] flying)
    #pragma unroll
    for (int ks = 0; ks < 2; ks++){
      short8 pa[2];
      #pragma unroll
      for (int i = 0; i < 2; i++)
        pa[i] = *(const short8*)((const char*)bufP + wave * 4096 + (i * 16 + l15) * 128 +
                                 (((ks * 4 + quad) ^ (l15 & 7)) * 16));
      short8 vb[8];
      #pragma unroll
      for (int ds = 0; ds < 8; ds++){
        const int row = ds * 16 + l15;         // d row
        const int ch = (ks * 4 + quad) ^ (row & 7);
        vb[ds] = *(const short8*)((const char*)bufV + row * 128 + ch * 16);
      }
      #pragma unroll
      for (int ds = 0; ds < 8; ds++)
        #pragma unroll
        for (int i = 0; i < 2; i++)
          o[i][ds] = __builtin_amdgcn_mfma_f32_16x16x32_bf16(pa[i], vb[ds], o[i][ds], 0, 0, 0);
    }

    __syncthreads();   // PV reads of bufV done; K[kt+1] drained

    // issue V[kt+1] — flies during next QK + softmax
    if (kt < 31){
      #pragma unroll
      for (int rr = 0; rr < 4; rr++){
        const int idx = rr * 256 + tid;
        const int row = idx >> 3, c = idx & 7;
        gl_lds16(vbh + (size_t)row * 2048 + (kt + 1) * 64 + ((c ^ (row & 7)) * 8),
                 (char*)bufV + rr * 4096 + wave * 1024);
      }
    }
  }

  // one cross-lane reduce of l over the 16-lane column group (quad preserved)
  #pragma unroll
  for (int i = 0; i < 2; i++)
    #pragma unroll
    for (int r = 0; r < 4; r++){
      #pragma unroll
      for (int off = 1; off < 16; off <<= 1) l_[i][r] += __shfl_xor(l_[i][r], off);
    }

  // epilogue: y[b, t, h*128 + d] = o / l
  const int b = bh >> 4, h = bh & 15;
  float inv[2][4];
  #pragma unroll
  for (int i = 0; i < 2; i++)
    #pragma unroll
    for (int r = 0; r < 4; r++) inv[i][r] = 1.0f / l_[i][r];
  #pragma unroll
  for (int i = 0; i < 2; i++)
    #pragma unroll
    for (int ds = 0; ds < 8; ds++)
      #pragma unroll
      for (int r = 0; r < 4; r++){
        const int t = qt * 128 + wave * 32 + i * 16 + quad * 4 + r;
        const int cc = h * 128 + ds * 16 + l15;
        y[((size_t)(b * 2048 + t)) * 2048 + cc] = f2bf(o[i][ds][r] * inv[i][r]);
      }
}

// ---------------------------------------------------------------- launcher
extern "C" void kernel_launch(void* const* d_in, const int* in_sizes, int n_in,
                              void* d_out, int out_size, void* d_ws, size_t ws_size,
                              hipStream_t stream) {
  const float* x    = (const float*)d_in[0];   // (2,2048,2048) fp32
  const float* Wa   = (const float*)d_in[1];   // (2048,6144) fp32
  const float* Wp   = (const float*)d_in[2];   // (2048,2048) fp32
  const float* cosb = (const float*)d_in[3];   // (2048,32) fp32
  const float* sinb = (const float*)d_in[4];   // (2048,32) fp32
  float* out = (float*)d_out;                  // (2,2048,2048) fp32
  char* ws = (char*)d_ws;

  u16* WaT = (u16*)(ws);                   // 6144x2048 bf16   25165824 B
  u16* WpT = (u16*)(ws + 25165824);        // 2048x2048 bf16    8388608 B
  u16* xb  = (u16*)(ws + 33554432);        // 4096x2048 bf16   16777216 B (dead after gemm1)
  u16* qkv = (u16*)(ws + 50331648);        // 4096x6144 bf16   50331648 B
  u16* qb  = (u16*)(ws + 100663296);       // (32,2048,128)    16777216 B
  u16* kb  = (u16*)(ws + 117440512);       //                  16777216 B
  u16* vTb = (u16*)(ws + 134217728);       // (32,128,2048)    16777216 B
  u16* yb  = (u16*)(ws + 33554432);        // 4096x2048 bf16 — reuses xb slot

  prep<<<20480, 256, 0, stream>>>(x, xb, Wa, WaT, Wp, WpT);
  gemm256x128<false><<<dim3(48, 16, 1), 512, 0, stream>>>(xb, WaT, qkv, 4096, 6144, 2048);
  rope_tv<<<40960, 256, 0, stream>>>(qkv, cosb, sinb, qb, kb, vTb);
  attn<<<512, 256, 0, stream>>>(qb, kb, vTb, yb);
  gemm_bt<true><<<dim3(16, 32, 1), 256, 0, stream>>>(yb, WpT, out, 4096, 2048, 2048);
}